// Round 9
// baseline (415.565 us; speedup 1.0000x reference)
//
#include <hip/hip_runtime.h>
#include <math.h>

// PointPWC multi-scale loss. B=2, scales N={8192,4096,2048,1024}.
// Inputs (B,3,N) fp32 channel-major: pc1_0..3, pc2_0..3, flow_0..3.
// Output: single fp32 scalar.
//
// R9: (1) pass C's scan (top-5 of p2, the expensive part) folded into the
// balanced 4-pass kernel -- its epilogue (needs cv2/cvw) becomes a tiny
// k_tail. Kills R8's k_cross latency starvation (2.65 waves/SIMD).
// (2) 2 queries/thread (wave = 128q x 1024c): DS:VALU 1:18 -> 1:48,
// fills/overheads halved, 2x per-wave ILP. SoA 3-plane LDS tile,
// uniform ds_read_b128 broadcast (4 cands / 3 reads).
// Passes interleaved via blockIdx&3 so every CU gets an A/B/C/D mix.

#define BLOCK 512
#define UNIT 1024    // candidates per wave-unit
#define NTOT 15360   // 8192+4096+2048+1024
#define MASKC 0xFFFFE000u
#define PB 170       // blocks per pass
#define STR 11       // merge-staging stride (odd -> 2-way alias only)

typedef unsigned int uint;

struct Params {
  const float* pc1[4];
  const float* pc2[4];
  const float* fl[4];
  float4* cv2;   // [B][NTOT]
  float4* cvw;   // [B][NTOT]
  float* ckeys;  // [B][NTOT][5] pass-C merged top-5 keys
  float* out;
};

// r in [0,170) -> scale s, batch b, 128-query-group base i0, cand lo.
__device__ __forceinline__ void decode(int r, int wv, int& s, int& b,
                                       int& i0, int& lo, int& N, int& cpw,
                                       int& off, float& alpha) {
  int rr;
  if (r < 128)      { s = 0; rr = r; }
  else if (r < 160) { s = 1; rr = r - 128; }
  else if (r < 168) { s = 2; rr = r - 160; }
  else              { s = 3; rr = r - 168; }
  N = 8192 >> s;
  cpw = 8 >> s;                        // candidate-ranges per qgroup
  int perb = 64 >> (2 * s);            // blocks per batch
  b = rr >> (6 - 2 * s);
  int chunk = rr & (perb - 1);
  int qg = (chunk << s) + (wv >> (3 - s));
  i0 = qg << 7;
  lo = (wv & (cpw - 1)) << 10;
  off = 16384 - (16384 >> s);          // {0, 8192, 12288, 14336}
  alpha = 0.02f * (float)(1 << s);
}

__device__ __forceinline__ float wave_sum(float v) {
  #pragma unroll
  for (int o = 32; o; o >>= 1) v += __shfl_down(v, o, 64);
  return v;
}

template <int K>
__device__ __forceinline__ void key_insert(float (&kd)[K], float kf) {
  #pragma unroll
  for (int m = K - 1; m >= 1; --m)
    kd[m] = __builtin_amdgcn_fmed3f(kf, kd[m - 1], kd[m]);
  kd[0] = fminf(kd[0], kf);
}

// 2 queries/thread scan of [lo, lo+UNIT). SoA x/y/z planes in this wave's
// private LDS region; reads are wave-uniform b128 (broadcast, 4 cands per
// 3 reads). WARP: candidates are p1+flow. PACK: idx in low 13 key bits.
template <int K, bool WARP, bool PACK>
__device__ void scan2(const float* px, const float* py, const float* pz,
                      const float* fx, const float* fy, const float* fz,
                      int lo,
                      float ax0, float ay0, float az0,
                      float ax1, float ay1, float az1,
                      float (&kd0)[K], float (&kd1)[K],
                      float* pl, int lane) {
  int j = lo + lane;
  float x = px[j], y = py[j], z = pz[j];
  if (WARP) { x += fx[j]; y += fy[j]; z += fz[j]; }
  for (int c0 = lo; c0 < lo + UNIT; c0 += 64) {
    pl[lane] = x; pl[64 + lane] = y; pl[128 + lane] = z;
    // same-wave fill->broadcast: DS pipe is in-order per wave
    asm volatile("s_waitcnt lgkmcnt(0)" ::: "memory");
    if (c0 + 64 < lo + UNIT) {   // prefetch next tile (rides vmcnt leash)
      int jn = j + 64;
      x = px[jn]; y = py[jn]; z = pz[jn];
      if (WARP) { x += fx[jn]; y += fy[jn]; z += fz[jn]; }
    }
    const float4* pv = (const float4*)pl;
    #pragma unroll 4
    for (int tc = 0; tc < 16; ++tc) {
      float4 xs = pv[tc], ys = pv[16 + tc], zs = pv[32 + tc];
      #pragma unroll
      for (int u = 0; u < 4; ++u) {
        float cx = (&xs.x)[u], cy = (&ys.x)[u], cz = (&zs.x)[u];
        uint iw = (uint)(c0 + tc * 4 + u);   // wave-uniform scalar
        float dx0 = ax0 - cx, dy0 = ay0 - cy, dz0 = az0 - cz;
        float d0 = fmaf(dx0, dx0, fmaf(dy0, dy0, dz0 * dz0));
        float dx1 = ax1 - cx, dy1 = ay1 - cy, dz1 = az1 - cz;
        float d1 = fmaf(dx1, dx1, fmaf(dy1, dy1, dz1 * dz1));
        if (PACK) {
          key_insert<K>(kd0,
              __uint_as_float((__float_as_uint(d0) & MASKC) | iw));
          key_insert<K>(kd1,
              __uint_as_float((__float_as_uint(d1) & MASKC) | iw));
        } else {
          kd0[0] = fminf(kd0[0], d0);
          kd1[0] = fminf(kd1[0], d1);
        }
      }
    }
    j += 64;
  }
}

// Stage both lists; leader wave (range 0 of its qgroup) merges its cpw
// waves' lists for all 128 queries. Returns true for leader threads.
template <int K>
__device__ __forceinline__ bool merge2(float (&kd0)[K], float (&kd1)[K],
                                       float* sm, int tid, int cpw) {
  int q = tid & 63, wv = tid >> 6;
  #pragma unroll
  for (int m = 0; m < K; ++m) {
    sm[(wv * 128 + q) * STR + m] = kd0[m];
    sm[(wv * 128 + 64 + q) * STR + m] = kd1[m];
  }
  __syncthreads();
  if (wv & (cpw - 1)) return false;
  for (int w = wv + 1; w < wv + cpw; ++w) {
    #pragma unroll
    for (int m = 0; m < K; ++m) {
      key_insert<K>(kd0, sm[(w * 128 + q) * STR + m]);
      key_insert<K>(kd1, sm[(w * 128 + 64 + q) * STR + m]);
    }
  }
  return true;
}

__global__ __launch_bounds__(1) void k_zero(float* out) { out[0] = 0.f; }

// pass 0 (A): self-KNN p2 k=10 -> cv2
// pass 1 (B): self-KNN p1 k=10 -> cvw + smoothness
// pass 2 (C): warp->p2 top-5 scan -> merged keys to ws (epilogue in k_tail)
// pass 3 (D): p2 -> warp min (dist2)
__global__ __launch_bounds__(BLOCK, 6) void k_fused(Params P) {
  __shared__ float planes[8 * 192];   // 6 KB: per-wave x/y/z planes
  __shared__ float sm[8 * 128 * STR]; // 45 KB merge staging
  int tid = threadIdx.x, q = tid & 63, wv = tid >> 6;
  int pass = blockIdx.x & 3, r = blockIdx.x >> 2;
  int s, b, i0, lo, N, cpw, off; float alpha;
  decode(r, wv, s, b, i0, lo, N, cpw, off, alpha);
  int iA = i0 + q, iB = i0 + 64 + q;
  float* pl = planes + wv * 192;

  const float* p1 = P.pc1[s] + b * 3 * N;
  const float* fl = P.fl[s] + b * 3 * N;
  const float* p2 = P.pc2[s] + b * 3 * N;

  if (pass == 0) {
    float ax0 = p2[iA], ay0 = p2[N + iA], az0 = p2[2 * N + iA];
    float ax1 = p2[iB], ay1 = p2[N + iB], az1 = p2[2 * N + iB];
    float kd0[10], kd1[10];
    #pragma unroll
    for (int m = 0; m < 10; ++m) { kd0[m] = 3.0e38f; kd1[m] = 3.0e38f; }
    scan2<10, false, true>(p2, p2 + N, p2 + 2 * N, nullptr, nullptr,
                           nullptr, lo, ax0, ay0, az0, ax1, ay1, az1,
                           kd0, kd1, pl, q);
    if (!merge2<10>(kd0, kd1, sm, tid, cpw)) return;
    #pragma unroll
    for (int h = 0; h < 2; ++h) {
      const float* kd = h ? kd1 : kd0;
      int i = h ? iB : iA;
      float ax = h ? ax1 : ax0, ay = h ? ay1 : ay0, az = h ? az1 : az0;
      float sx = 0.f, sy = 0.f, sz = 0.f;
      #pragma unroll
      for (int m = 0; m < 10; ++m) {
        int j = (int)(__float_as_uint(kd[m]) & 0x1FFFu);
        sx += p2[j]; sy += p2[N + j]; sz += p2[2 * N + j];
      }
      const float inv9 = 1.f / 9.f;
      P.cv2[b * NTOT + off + i] = make_float4((sx - 10.f * ax) * inv9,
                                              (sy - 10.f * ay) * inv9,
                                              (sz - 10.f * az) * inv9, 0.f);
    }
  } else if (pass == 1) {
    float ax0 = p1[iA], ay0 = p1[N + iA], az0 = p1[2 * N + iA];
    float ax1 = p1[iB], ay1 = p1[N + iB], az1 = p1[2 * N + iB];
    float kd0[10], kd1[10];
    #pragma unroll
    for (int m = 0; m < 10; ++m) { kd0[m] = 3.0e38f; kd1[m] = 3.0e38f; }
    scan2<10, false, true>(p1, p1 + N, p1 + 2 * N, nullptr, nullptr,
                           nullptr, lo, ax0, ay0, az0, ax1, ay1, az1,
                           kd0, kd1, pl, q);
    if (!merge2<10>(kd0, kd1, sm, tid, cpw)) return;
    float smsum = 0.f;
    #pragma unroll
    for (int h = 0; h < 2; ++h) {
      const float* kd = h ? kd1 : kd0;
      int i = h ? iB : iA;
      float ax = h ? ax1 : ax0, ay = h ? ay1 : ay0, az = h ? az1 : az0;
      float fix = fl[i], fiy = fl[N + i], fiz = fl[2 * N + i];
      float wix = ax + fix, wiy = ay + fiy, wiz = az + fiz;
      float sx = 0.f, sy = 0.f, sz = 0.f, smooth = 0.f;
      float dmax = -1.f, worst = 0.f;
      #pragma unroll
      for (int m = 0; m < 10; ++m) {
        int j = (int)(__float_as_uint(kd[m]) & 0x1FFFu);
        float px = p1[j], py = p1[N + j], pz = p1[2 * N + j];
        float flx = fl[j], fly = fl[N + j], flz = fl[2 * N + j];
        sx += px + flx; sy += py + fly; sz += pz + flz;
        float ddx = px - ax, ddy = py - ay, ddz = pz - az;
        float d = fmaf(ddx, ddx, fmaf(ddy, ddy, ddz * ddz));  // exact
        float gx = flx - fix, gy = fly - fiy, gz = flz - fiz;
        float term = sqrtf(fmaf(gx, gx, fmaf(gy, gy, gz * gz)));
        smooth += term;
        if (d > dmax) { dmax = d; worst = term; }  // drop farthest (k9)
      }
      smooth -= worst;
      const float inv9 = 1.f / 9.f;
      P.cvw[b * NTOT + off + i] = make_float4((sx - 10.f * wix) * inv9,
                                              (sy - 10.f * wiy) * inv9,
                                              (sz - 10.f * wiz) * inv9, 0.f);
      smsum += smooth;
    }
    float ssum = wave_sum(smsum * (1.f / 8.f));
    if (q == 0) atomicAdd(P.out, alpha * 0.5f * ssum);
  } else if (pass == 2) {
    float ax0 = p1[iA] + fl[iA], ay0 = p1[N + iA] + fl[N + iA],
          az0 = p1[2 * N + iA] + fl[2 * N + iA];
    float ax1 = p1[iB] + fl[iB], ay1 = p1[N + iB] + fl[N + iB],
          az1 = p1[2 * N + iB] + fl[2 * N + iB];
    float kd0[5], kd1[5];
    #pragma unroll
    for (int m = 0; m < 5; ++m) { kd0[m] = 3.0e38f; kd1[m] = 3.0e38f; }
    scan2<5, false, true>(p2, p2 + N, p2 + 2 * N, nullptr, nullptr,
                          nullptr, lo, ax0, ay0, az0, ax1, ay1, az1,
                          kd0, kd1, pl, q);
    if (!merge2<5>(kd0, kd1, sm, tid, cpw)) return;
    #pragma unroll
    for (int m = 0; m < 5; ++m) {
      P.ckeys[(b * NTOT + off + iA) * 5 + m] = kd0[m];
      P.ckeys[(b * NTOT + off + iB) * 5 + m] = kd1[m];
    }
  } else {
    float ax0 = p2[iA], ay0 = p2[N + iA], az0 = p2[2 * N + iA];
    float ax1 = p2[iB], ay1 = p2[N + iB], az1 = p2[2 * N + iB];
    float kd0[1], kd1[1];
    kd0[0] = 3.0e38f; kd1[0] = 3.0e38f;
    scan2<1, true, false>(p1, p1 + N, p1 + 2 * N, fl, fl + N, fl + 2 * N,
                          lo, ax0, ay0, az0, ax1, ay1, az1, kd0, kd1, pl, q);
    if (!merge2<1>(kd0, kd1, sm, tid, cpw)) return;
    float msum = wave_sum(kd0[0] + kd1[0]);
    if (q == 0) atomicAdd(P.out, alpha * 0.5f * msum);
  }
}

// Tail: pass-C epilogue. One thread per query: top-5 exact distances,
// inverse-distance cv2 interpolation, curvature + chamfer(dist1) atomic.
__global__ __launch_bounds__(256) void k_tail(Params P) {
  int g = blockIdx.x * 256 + threadIdx.x;   // [0, 30720)
  int b = (g >= NTOT) ? 1 : 0;
  int t = g - b * NTOT;
  int s = (t < 8192) ? 0 : (t < 12288) ? 1 : (t < 14336) ? 2 : 3;
  int off = 16384 - (16384 >> s);
  int N = 8192 >> s;
  int i = t - off;
  float alpha = 0.02f * (float)(1 << s);
  const float* p1 = P.pc1[s] + b * 3 * N;
  const float* fl = P.fl[s] + b * 3 * N;
  const float* p2 = P.pc2[s] + b * 3 * N;
  float ax = p1[i] + fl[i], ay = p1[N + i] + fl[N + i],
        az = p1[2 * N + i] + fl[2 * N + i];
  float dist1 = 3.0e38f, wsum = 0.f, ix = 0.f, iy = 0.f, iz = 0.f;
  #pragma unroll
  for (int m = 0; m < 5; ++m) {
    float key = P.ckeys[(b * NTOT + t) * 5 + m];
    int j = (int)(__float_as_uint(key) & 0x1FFFu);
    float px = p2[j], py = p2[N + j], pz = p2[2 * N + j];
    float ddx = px - ax, ddy = py - ay, ddz = pz - az;
    float d = fmaf(ddx, ddx, fmaf(ddy, ddy, ddz * ddz));  // exact
    dist1 = fminf(dist1, d);
    float w = 1.f / (d + 1e-8f);
    wsum += w;
    float4 cv = P.cv2[b * NTOT + t - i + j];   // off + j
    ix += w * cv.x; iy += w * cv.y; iz += w * cv.z;
  }
  float inv = 1.f / wsum;
  ix *= inv; iy *= inv; iz *= inv;
  float4 cw = P.cvw[b * NTOT + t];
  float ex = ix - cw.x, ey = iy - cw.y, ez = iz - cw.z;
  float curv = fmaf(ex, ex, fmaf(ey, ey, ez * ez));
  float v = alpha * (dist1 + 0.3f * curv);   // per-lane alpha (boundaries)
  float csum = wave_sum(v);
  if ((threadIdx.x & 63) == 0) atomicAdd(P.out, 0.5f * csum);
}

extern "C" void kernel_launch(void* const* d_in, const int* in_sizes, int n_in,
                              void* d_out, int out_size, void* d_ws,
                              size_t ws_size, hipStream_t stream) {
  Params P;
  for (int s = 0; s < 4; ++s) {
    P.pc1[s] = (const float*)d_in[s];
    P.pc2[s] = (const float*)d_in[4 + s];
    P.fl[s]  = (const float*)d_in[8 + s];
  }
  P.cv2 = (float4*)d_ws;
  P.cvw = P.cv2 + 2 * NTOT;
  P.ckeys = (float*)(P.cvw + 2 * NTOT);   // 2*NTOT*5 floats = 614 KB
  P.out = (float*)d_out;

  k_zero<<<dim3(1), dim3(1), 0, stream>>>(P.out);
  k_fused<<<dim3(4 * PB), dim3(BLOCK), 0, stream>>>(P);
  k_tail<<<dim3(120), dim3(256), 0, stream>>>(P);
}

// Round 10
// 392.752 us; speedup vs baseline: 1.0581x; 1.0581x over previous
//
#include <hip/hip_runtime.h>
#include <math.h>

// PointPWC multi-scale loss. B=2, scales N={8192,4096,2048,1024}.
// Inputs (B,3,N) fp32 channel-major: pc1_0..3, pc2_0..3, flow_0..3.
// Output: single fp32 scalar.
//
// R10: R8's proven scan engine (1 query/thread, even/odd dual med3
// chains, AoS float4 LDS tile -> guaranteed-aligned ds_read_b128
// broadcast) + R9's structurally-sound pass-C folding (C's top-5 scan is
// a 4th balanced pass writing keys to ws; epilogue in tiny k_tail).
// R9's regression traced to its float->float4 cast LDS tile (4-byte
// alignment -> ds_read_b32 x4 per vec -> LDS pipe saturated, shared-
// resource stall). 1360 uniform blocks, passes interleaved blockIdx&3.

#define BLOCK 512
#define UNIT 1024    // candidates per wave-unit
#define NTOT 15360   // 8192+4096+2048+1024
#define MASKC 0xFFFFE000u
#define PB 340       // blocks per pass
#define STR 11       // merge-staging stride (odd -> 2-way alias only)

typedef unsigned int uint;

struct Params {
  const float* pc1[4];
  const float* pc2[4];
  const float* fl[4];
  float4* cv2;   // [B][NTOT]
  float4* cvw;   // [B][NTOT]
  float* ckeys;  // [B][NTOT][5] pass-C merged top-5 keys
  float* out;
};

// r in [0,340) -> scale s, batch b, 64-query-group base i0, cand lo.
__device__ __forceinline__ void decode(int r, int wv, int& s, int& b,
                                       int& i0, int& lo, int& N, int& cpw,
                                       int& off, float& alpha) {
  int rr;
  if (r < 256)      { s = 0; rr = r; }
  else if (r < 320) { s = 1; rr = r - 256; }
  else if (r < 336) { s = 2; rr = r - 320; }
  else              { s = 3; rr = r - 336; }
  N = 8192 >> s;
  cpw = 8 >> s;                       // candidate-ranges per qgroup
  int perb = 128 >> (2 * s);          // blocks per batch
  b = rr >> (7 - 2 * s);
  int chunk = rr & (perb - 1);
  int qg = (chunk << s) + (wv >> (3 - s));
  i0 = qg << 6;
  lo = (wv & (cpw - 1)) << 10;
  off = 16384 - (16384 >> s);         // {0, 8192, 12288, 14336}
  alpha = 0.02f * (float)(1 << s);
}

__device__ __forceinline__ float wave_sum(float v) {
  #pragma unroll
  for (int o = 32; o; o >>= 1) v += __shfl_down(v, o, 64);
  return v;
}

template <int K>
__device__ __forceinline__ void key_insert(float (&kd)[K], float kf) {
  #pragma unroll
  for (int m = K - 1; m >= 1; --m)
    kd[m] = __builtin_amdgcn_fmed3f(kf, kd[m - 1], kd[m]);
  kd[0] = fminf(kd[0], kf);
}

template <int K>
__device__ __forceinline__ void merge_pair(float (&a)[K], const float (&b)[K]) {
  #pragma unroll
  for (int m = 0; m < K; ++m) key_insert<K>(a, b[m]);
}

__device__ __forceinline__ float pack_key(float d, float iw) {
  return __uint_as_float((__float_as_uint(d) & MASKC) | __float_as_uint(iw));
}

// One unit: 1 query/thread, 2 alternating chains (even/odd candidates),
// candidates broadcast from this wave's private AoS float4 LDS tile
// (16B-aligned type -> ds_read_b128 at wave-uniform address).
template <int K, bool WARP, bool PACK>
__device__ void scan_u(const float* px, const float* py, const float* pz,
                       const float* fx, const float* fy, const float* fz,
                       int lo, float ax, float ay, float az,
                       float (&a)[K], float (&b)[K], float4* tile,
                       int lane) {
  int j = lo + lane;
  float x = px[j], y = py[j], z = pz[j];
  if (WARP) { x += fx[j]; y += fy[j]; z += fz[j]; }
  for (int c0 = lo; c0 < lo + UNIT; c0 += 64) {
    tile[lane] = make_float4(x, y, z, __uint_as_float((uint)(c0 + lane)));
    // same-wave fill->broadcast: DS pipe is in-order per wave
    asm volatile("s_waitcnt lgkmcnt(0)" ::: "memory");
    if (c0 + 64 < lo + UNIT) {   // prefetch next tile (rides vmcnt leash)
      int jn = j + 64;
      x = px[jn]; y = py[jn]; z = pz[jn];
      if (WARP) { x += fx[jn]; y += fy[jn]; z += fz[jn]; }
    }
    #pragma unroll 8
    for (int t = 0; t < 64; t += 2) {
      float4 cA = tile[t];
      float4 cB = tile[t + 1];
      float dxa = ax - cA.x, dya = ay - cA.y, dza = az - cA.z;
      float dA = fmaf(dxa, dxa, fmaf(dya, dya, dza * dza));
      float dxb = ax - cB.x, dyb = ay - cB.y, dzb = az - cB.z;
      float dB = fmaf(dxb, dxb, fmaf(dyb, dyb, dzb * dzb));
      if (PACK) {
        key_insert<K>(a, pack_key(dA, cA.w));
        key_insert<K>(b, pack_key(dB, cB.w));
      } else {
        a[0] = fminf(a[0], dA);
        b[0] = fminf(b[0], dB);
      }
    }
    j += 64;
  }
}

// Stage per-thread list; group leader (wave with range 0) merges its
// qgroup's cpw lists. Returns true for leader threads.
template <int K>
__device__ __forceinline__ bool merge_group(float (&a)[K], float* sm,
                                            int tid, int cpw) {
  int q = tid & 63, wv = tid >> 6;
  #pragma unroll
  for (int m = 0; m < K; ++m) sm[(wv * 64 + q) * STR + m] = a[m];
  __syncthreads();
  if (wv & (cpw - 1)) return false;
  for (int w = wv + 1; w < wv + cpw; ++w)
    #pragma unroll
    for (int m = 0; m < K; ++m)
      key_insert<K>(a, sm[(w * 64 + q) * STR + m]);
  return true;
}

__global__ __launch_bounds__(1) void k_zero(float* out) { out[0] = 0.f; }

// pass 0 (A): self-KNN p2 k=10 -> cv2
// pass 1 (B): self-KNN p1 k=10 -> cvw + smoothness
// pass 2 (C): warp->p2 top-5 scan -> merged keys to ws (epilogue: k_tail)
// pass 3 (D): p2 -> warp min (dist2)
__global__ __launch_bounds__(BLOCK, 8) void k_fused(Params P) {
  __shared__ float4 tiles[8][64];        // 8 KB
  __shared__ float sm[8 * 64 * STR];     // 22.5 KB
  int tid = threadIdx.x, q = tid & 63, wv = tid >> 6;
  int pass = blockIdx.x & 3, r = blockIdx.x >> 2;
  int s, b, i0, lo, N, cpw, off; float alpha;
  decode(r, wv, s, b, i0, lo, N, cpw, off, alpha);
  int i = i0 + q;
  float4* tile = tiles[wv];

  const float* p1 = P.pc1[s] + b * 3 * N;
  const float* fl = P.fl[s] + b * 3 * N;
  const float* p2 = P.pc2[s] + b * 3 * N;

  if (pass == 0) {
    float ax = p2[i], ay = p2[N + i], az = p2[2 * N + i];
    float a[10], bb[10];
    #pragma unroll
    for (int m = 0; m < 10; ++m) { a[m] = 3.0e38f; bb[m] = 3.0e38f; }
    scan_u<10, false, true>(p2, p2 + N, p2 + 2 * N, nullptr, nullptr,
                            nullptr, lo, ax, ay, az, a, bb, tile, q);
    merge_pair<10>(a, bb);
    if (!merge_group<10>(a, sm, tid, cpw)) return;
    float sx = 0.f, sy = 0.f, sz = 0.f;
    #pragma unroll
    for (int m = 0; m < 10; ++m) {
      int j = (int)(__float_as_uint(a[m]) & 0x1FFFu);
      sx += p2[j]; sy += p2[N + j]; sz += p2[2 * N + j];
    }
    const float inv9 = 1.f / 9.f;
    P.cv2[b * NTOT + off + i] = make_float4((sx - 10.f * ax) * inv9,
                                            (sy - 10.f * ay) * inv9,
                                            (sz - 10.f * az) * inv9, 0.f);
  } else if (pass == 1) {
    float ax = p1[i], ay = p1[N + i], az = p1[2 * N + i];
    float a[10], bb[10];
    #pragma unroll
    for (int m = 0; m < 10; ++m) { a[m] = 3.0e38f; bb[m] = 3.0e38f; }
    scan_u<10, false, true>(p1, p1 + N, p1 + 2 * N, nullptr, nullptr,
                            nullptr, lo, ax, ay, az, a, bb, tile, q);
    merge_pair<10>(a, bb);
    if (!merge_group<10>(a, sm, tid, cpw)) return;
    float fix = fl[i], fiy = fl[N + i], fiz = fl[2 * N + i];
    float wix = ax + fix, wiy = ay + fiy, wiz = az + fiz;
    float sx = 0.f, sy = 0.f, sz = 0.f, smooth = 0.f;
    float dmax = -1.f, worst = 0.f;
    #pragma unroll
    for (int m = 0; m < 10; ++m) {
      int j = (int)(__float_as_uint(a[m]) & 0x1FFFu);
      float px = p1[j], py = p1[N + j], pz = p1[2 * N + j];
      float flx = fl[j], fly = fl[N + j], flz = fl[2 * N + j];
      sx += px + flx; sy += py + fly; sz += pz + flz;
      float ddx = px - ax, ddy = py - ay, ddz = pz - az;
      float d = fmaf(ddx, ddx, fmaf(ddy, ddy, ddz * ddz));  // exact
      float gx = flx - fix, gy = fly - fiy, gz = flz - fiz;
      float term = sqrtf(fmaf(gx, gx, fmaf(gy, gy, gz * gz)));
      smooth += term;
      if (d > dmax) { dmax = d; worst = term; }  // drop farthest (k9)
    }
    smooth -= worst;
    const float inv9 = 1.f / 9.f;
    P.cvw[b * NTOT + off + i] = make_float4((sx - 10.f * wix) * inv9,
                                            (sy - 10.f * wiy) * inv9,
                                            (sz - 10.f * wiz) * inv9, 0.f);
    float ssum = wave_sum(smooth * (1.f / 8.f));
    if (q == 0) atomicAdd(P.out, alpha * 0.5f * ssum);
  } else if (pass == 2) {
    float ax = p1[i] + fl[i], ay = p1[N + i] + fl[N + i],
          az = p1[2 * N + i] + fl[2 * N + i];
    float a[5], bb[5];
    #pragma unroll
    for (int m = 0; m < 5; ++m) { a[m] = 3.0e38f; bb[m] = 3.0e38f; }
    scan_u<5, false, true>(p2, p2 + N, p2 + 2 * N, nullptr, nullptr,
                           nullptr, lo, ax, ay, az, a, bb, tile, q);
    merge_pair<5>(a, bb);
    if (!merge_group<5>(a, sm, tid, cpw)) return;
    #pragma unroll
    for (int m = 0; m < 5; ++m)
      P.ckeys[(b * NTOT + off + i) * 5 + m] = a[m];
  } else {
    float ax = p2[i], ay = p2[N + i], az = p2[2 * N + i];
    float a[1], bb[1];
    a[0] = 3.0e38f; bb[0] = 3.0e38f;
    scan_u<1, true, false>(p1, p1 + N, p1 + 2 * N, fl, fl + N, fl + 2 * N,
                           lo, ax, ay, az, a, bb, tile, q);
    merge_pair<1>(a, bb);
    if (!merge_group<1>(a, sm, tid, cpw)) return;
    float msum = wave_sum(a[0]);
    if (q == 0) atomicAdd(P.out, alpha * 0.5f * msum);
  }
}

// Tail: pass-C epilogue. One thread per query: top-5 exact distances,
// inverse-distance cv2 interpolation, curvature + chamfer(dist1) atomic.
__global__ __launch_bounds__(256) void k_tail(Params P) {
  int g = blockIdx.x * 256 + threadIdx.x;   // [0, 30720)
  int b = (g >= NTOT) ? 1 : 0;
  int t = g - b * NTOT;
  int s = (t < 8192) ? 0 : (t < 12288) ? 1 : (t < 14336) ? 2 : 3;
  int off = 16384 - (16384 >> s);
  int N = 8192 >> s;
  int i = t - off;
  float alpha = 0.02f * (float)(1 << s);
  const float* p1 = P.pc1[s] + b * 3 * N;
  const float* fl = P.fl[s] + b * 3 * N;
  const float* p2 = P.pc2[s] + b * 3 * N;
  float ax = p1[i] + fl[i], ay = p1[N + i] + fl[N + i],
        az = p1[2 * N + i] + fl[2 * N + i];
  float dist1 = 3.0e38f, wsum = 0.f, ix = 0.f, iy = 0.f, iz = 0.f;
  #pragma unroll
  for (int m = 0; m < 5; ++m) {
    float key = P.ckeys[(b * NTOT + t) * 5 + m];
    int j = (int)(__float_as_uint(key) & 0x1FFFu);
    float px = p2[j], py = p2[N + j], pz = p2[2 * N + j];
    float ddx = px - ax, ddy = py - ay, ddz = pz - az;
    float d = fmaf(ddx, ddx, fmaf(ddy, ddy, ddz * ddz));  // exact
    dist1 = fminf(dist1, d);
    float w = 1.f / (d + 1e-8f);
    wsum += w;
    float4 cv = P.cv2[b * NTOT + off + j];
    ix += w * cv.x; iy += w * cv.y; iz += w * cv.z;
  }
  float inv = 1.f / wsum;
  ix *= inv; iy *= inv; iz *= inv;
  float4 cw = P.cvw[b * NTOT + t];
  float ex = ix - cw.x, ey = iy - cw.y, ez = iz - cw.z;
  float curv = fmaf(ex, ex, fmaf(ey, ey, ez * ez));
  float v = alpha * (dist1 + 0.3f * curv);   // per-lane alpha (boundaries)
  float csum = wave_sum(v);
  if ((threadIdx.x & 63) == 0) atomicAdd(P.out, 0.5f * csum);
}

extern "C" void kernel_launch(void* const* d_in, const int* in_sizes, int n_in,
                              void* d_out, int out_size, void* d_ws,
                              size_t ws_size, hipStream_t stream) {
  Params P;
  for (int s = 0; s < 4; ++s) {
    P.pc1[s] = (const float*)d_in[s];
    P.pc2[s] = (const float*)d_in[4 + s];
    P.fl[s]  = (const float*)d_in[8 + s];
  }
  P.cv2 = (float4*)d_ws;
  P.cvw = P.cv2 + 2 * NTOT;
  P.ckeys = (float*)(P.cvw + 2 * NTOT);   // 2*NTOT*5 floats = 614 KB
  P.out = (float*)d_out;

  k_zero<<<dim3(1), dim3(1), 0, stream>>>(P.out);
  k_fused<<<dim3(4 * PB), dim3(BLOCK), 0, stream>>>(P);
  k_tail<<<dim3(120), dim3(256), 0, stream>>>(P);
}